// Round 6
// baseline (402.865 us; speedup 1.0000x reference)
//
#include <hip/hip_runtime.h>
#include <hip/hip_bf16.h>

// ---------------------------------------------------------------------------
// GraphSAGE (3x SAGEConv mean + linear head), CSR gather formulation.
// bf16 hidden activations + bf16 aggregates; layers 2/3 = MFMA bf16 GEMM
// (K=256, fragments straight from global, no LDS/barriers).
// R6: layer16 node-major + vectorized (was latency-bound at 72us);
//     aggregate128 4 nodes/wave + unroll-2 (8 outstanding loads/wave).
// ---------------------------------------------------------------------------

#define SCAN_CHUNK 2048

typedef unsigned short bf16_t;
typedef unsigned int uint32;
typedef __attribute__((ext_vector_type(8))) short bf16x8;   // 8 bf16 = 4 VGPRs
typedef __attribute__((ext_vector_type(4))) float f32x4;

__device__ __forceinline__ bf16_t f2bf(float f) {
    uint32 u = __float_as_uint(f);
    u += 0x7fff + ((u >> 16) & 1);           // round-to-nearest-even
    return (bf16_t)(u >> 16);
}
__device__ __forceinline__ float bf2f(bf16_t b) {
    return __uint_as_float((uint32)b << 16);
}

__global__ void zero_int_kernel(int* __restrict__ p, int n) {
    int i = blockIdx.x * 256 + threadIdx.x;
    if (i < n) p[i] = 0;
}

__global__ void count_deg_kernel(const int* __restrict__ dst, int* __restrict__ deg, int E) {
    int e = blockIdx.x * 256 + threadIdx.x;
    if (e < E) atomicAdd(&deg[dst[e]], 1);
}

__global__ __launch_bounds__(256) void scan_partial_kernel(
    const int* __restrict__ deg, int* __restrict__ blocksum, int N) {
    __shared__ int s[256];
    const int t = threadIdx.x;
    const int base = blockIdx.x * SCAN_CHUNK + t * 8;
    int sum = 0;
    #pragma unroll
    for (int j = 0; j < 8; ++j) {
        int i = base + j;
        if (i < N) sum += deg[i];
    }
    s[t] = sum;
    __syncthreads();
    #pragma unroll
    for (int off = 128; off > 0; off >>= 1) {
        if (t < off) s[t] += s[t + off];
        __syncthreads();
    }
    if (t == 0) blocksum[blockIdx.x] = s[0];
}

__global__ __launch_bounds__(256) void scan_final_kernel(
    const int* __restrict__ deg, const int* __restrict__ blocksum,
    int* __restrict__ rowptr, int* __restrict__ cursor,
    float* __restrict__ inv, int N) {
    __shared__ int s[256];
    __shared__ int blockoff_s;
    const int t = threadIdx.x;
    if (t == 0) {
        int off = 0;
        for (int b = 0; b < (int)blockIdx.x; ++b) off += blocksum[b];
        blockoff_s = off;
    }
    const int base = blockIdx.x * SCAN_CHUNK + t * 8;
    int v[8];
    int sum = 0;
    #pragma unroll
    for (int j = 0; j < 8; ++j) {
        int i = base + j;
        v[j] = (i < N) ? deg[i] : 0;
        sum += v[j];
    }
    s[t] = sum;
    __syncthreads();
    for (int off = 1; off < 256; off <<= 1) {
        int val = (t >= off) ? s[t - off] : 0;
        __syncthreads();
        s[t] += val;
        __syncthreads();
    }
    int run = blockoff_s + ((t == 0) ? 0 : s[t - 1]);
    #pragma unroll
    for (int j = 0; j < 8; ++j) {
        int i = base + j;
        if (i < N) {
            rowptr[i] = run;
            cursor[i] = run;
            inv[i] = 1.0f / (float)max(v[j], 1);
            run += v[j];
        }
    }
    if ((int)blockIdx.x == (int)gridDim.x - 1 && t == 255) rowptr[N] = run;
}

__global__ void fill_csr_kernel(const int* __restrict__ src, const int* __restrict__ dst,
                                int* __restrict__ cursor, int* __restrict__ col, int E) {
    int e = blockIdx.x * 256 + threadIdx.x;
    if (e >= E) return;
    int pos = atomicAdd(&cursor[dst[e]], 1);
    col[pos] = src[e];
}

// combine Wl|Wr (fp32, [128][128] each) -> wbf [128 o][256 k] bf16
__global__ void convert_w_kernel(const float* __restrict__ Wl, const float* __restrict__ Wr,
                                 bf16_t* __restrict__ wbf) {
    int idx = blockIdx.x * 256 + threadIdx.x;   // 0..32767
    int o = idx >> 8;
    int k = idx & 255;
    float v = (k < 128) ? Wl[o * 128 + k] : Wr[o * 128 + k - 128];
    wbf[idx] = f2bf(v);
}

// 16-feat mean aggregate over fp32 x -> fp32 agg16
__global__ __launch_bounds__(256) void aggregate16_kernel(
    const float* __restrict__ x, const int* __restrict__ rowptr,
    const int* __restrict__ col, const float* __restrict__ inv,
    float* __restrict__ agg, int N) {
    const int t = threadIdx.x;
    const int node = blockIdx.x * 16 + (t >> 4);
    const int f = t & 15;
    if (node >= N) return;
    const int lo = rowptr[node], hi = rowptr[node + 1];
    float acc = 0.0f;
    for (int e = lo; e < hi; ++e)
        acc += x[col[e] * 16 + f];
    agg[node * 16 + f] = acc * inv[node];
}

// 128-feat mean aggregate over bf16 h -> bf16 agg.
// 4 nodes per wave (16 lanes x 16B = 256B row), unroll-2: up to 8
// independent row loads in flight per wave; 16B/lane loads and stores.
__global__ __launch_bounds__(256) void aggregate128_kernel(
    const bf16_t* __restrict__ h, const int* __restrict__ rowptr,
    const int* __restrict__ col, const float* __restrict__ inv,
    bf16_t* __restrict__ aggb, int N) {
    const int t = threadIdx.x;
    const int node = blockIdx.x * 16 + (t >> 4);   // 16 nodes per 256-thr block
    const int li = t & 15;                         // lane-in-group
    if (node >= N) return;
    const int lo = rowptr[node], hi = rowptr[node + 1];
    float acc[8];
    #pragma unroll
    for (int j = 0; j < 8; ++j) acc[j] = 0.0f;
    int e = lo;
    for (; e + 1 < hi; e += 2) {
        int s0 = col[e], s1 = col[e + 1];
        uint4 v0 = *(const uint4*)&h[(size_t)s0 * 128 + li * 8];
        uint4 v1 = *(const uint4*)&h[(size_t)s1 * 128 + li * 8];
        acc[0] += bf2f((bf16_t)(v0.x & 0xffff)); acc[1] += bf2f((bf16_t)(v0.x >> 16));
        acc[2] += bf2f((bf16_t)(v0.y & 0xffff)); acc[3] += bf2f((bf16_t)(v0.y >> 16));
        acc[4] += bf2f((bf16_t)(v0.z & 0xffff)); acc[5] += bf2f((bf16_t)(v0.z >> 16));
        acc[6] += bf2f((bf16_t)(v0.w & 0xffff)); acc[7] += bf2f((bf16_t)(v0.w >> 16));
        acc[0] += bf2f((bf16_t)(v1.x & 0xffff)); acc[1] += bf2f((bf16_t)(v1.x >> 16));
        acc[2] += bf2f((bf16_t)(v1.y & 0xffff)); acc[3] += bf2f((bf16_t)(v1.y >> 16));
        acc[4] += bf2f((bf16_t)(v1.z & 0xffff)); acc[5] += bf2f((bf16_t)(v1.z >> 16));
        acc[6] += bf2f((bf16_t)(v1.w & 0xffff)); acc[7] += bf2f((bf16_t)(v1.w >> 16));
    }
    if (e < hi) {
        uint4 v0 = *(const uint4*)&h[(size_t)col[e] * 128 + li * 8];
        acc[0] += bf2f((bf16_t)(v0.x & 0xffff)); acc[1] += bf2f((bf16_t)(v0.x >> 16));
        acc[2] += bf2f((bf16_t)(v0.y & 0xffff)); acc[3] += bf2f((bf16_t)(v0.y >> 16));
        acc[4] += bf2f((bf16_t)(v0.z & 0xffff)); acc[5] += bf2f((bf16_t)(v0.z >> 16));
        acc[6] += bf2f((bf16_t)(v0.w & 0xffff)); acc[7] += bf2f((bf16_t)(v0.w >> 16));
    }
    const float iv = inv[node];
    uint4 pk;
    pk.x = (uint32)f2bf(acc[0] * iv) | ((uint32)f2bf(acc[1] * iv) << 16);
    pk.y = (uint32)f2bf(acc[2] * iv) | ((uint32)f2bf(acc[3] * iv) << 16);
    pk.z = (uint32)f2bf(acc[4] * iv) | ((uint32)f2bf(acc[5] * iv) << 16);
    pk.w = (uint32)f2bf(acc[6] * iv) | ((uint32)f2bf(acc[7] * iv) << 16);
    *(uint4*)&aggb[(size_t)node * 128 + li * 8] = pk;
}

// layer 1: 16 -> 128, node-major. Thread = (node, 8-output group):
// row reads as float4, weights float4 from L1-resident 8KB arrays,
// one 16B (8x bf16) coalesced store per thread.
__global__ __launch_bounds__(256) void layer16_kernel(
    const float* __restrict__ agg16, const float* __restrict__ x,
    const float* __restrict__ Wl, const float* __restrict__ Wr,
    const float* __restrict__ bias, bf16_t* __restrict__ hout, int n) {
    const int idx = blockIdx.x * 256 + threadIdx.x;
    const int node = idx >> 4;
    const int og = (idx & 15) * 8;
    if (node >= n) return;

    float4 a0 = *(const float4*)&agg16[node * 16 + 0];
    float4 a1 = *(const float4*)&agg16[node * 16 + 4];
    float4 a2 = *(const float4*)&agg16[node * 16 + 8];
    float4 a3 = *(const float4*)&agg16[node * 16 + 12];
    float4 x0 = *(const float4*)&x[node * 16 + 0];
    float4 x1 = *(const float4*)&x[node * 16 + 4];
    float4 x2 = *(const float4*)&x[node * 16 + 8];
    float4 x3 = *(const float4*)&x[node * 16 + 12];

    uint4 pk;
    uint32* pko = (uint32*)&pk;
    #pragma unroll
    for (int j = 0; j < 8; ++j) {
        int o = og + j;
        const float* wl = Wl + o * 16;
        const float* wr = Wr + o * 16;
        float4 l0 = *(const float4*)&wl[0], l1 = *(const float4*)&wl[4];
        float4 l2 = *(const float4*)&wl[8], l3 = *(const float4*)&wl[12];
        float4 r0 = *(const float4*)&wr[0], r1 = *(const float4*)&wr[4];
        float4 r2 = *(const float4*)&wr[8], r3 = *(const float4*)&wr[12];
        float acc = bias[o];
        acc = fmaf(a0.x, l0.x, fmaf(a0.y, l0.y, fmaf(a0.z, l0.z, fmaf(a0.w, l0.w, acc))));
        acc = fmaf(a1.x, l1.x, fmaf(a1.y, l1.y, fmaf(a1.z, l1.z, fmaf(a1.w, l1.w, acc))));
        acc = fmaf(a2.x, l2.x, fmaf(a2.y, l2.y, fmaf(a2.z, l2.z, fmaf(a2.w, l2.w, acc))));
        acc = fmaf(a3.x, l3.x, fmaf(a3.y, l3.y, fmaf(a3.z, l3.z, fmaf(a3.w, l3.w, acc))));
        acc = fmaf(x0.x, r0.x, fmaf(x0.y, r0.y, fmaf(x0.z, r0.z, fmaf(x0.w, r0.w, acc))));
        acc = fmaf(x1.x, r1.x, fmaf(x1.y, r1.y, fmaf(x1.z, r1.z, fmaf(x1.w, r1.w, acc))));
        acc = fmaf(x2.x, r2.x, fmaf(x2.y, r2.y, fmaf(x2.z, r2.z, fmaf(x2.w, r2.w, acc))));
        acc = fmaf(x3.x, r3.x, fmaf(x3.y, r3.y, fmaf(x3.z, r3.z, fmaf(x3.w, r3.w, acc))));
        bf16_t hb = f2bf(fmaxf(acc, 0.0f));
        if (j & 1) pko[j >> 1] |= ((uint32)hb << 16);
        else       pko[j >> 1] = (uint32)hb;
    }
    *(uint4*)&hout[(size_t)node * 128 + og] = pk;
}

// layers 2/3 as MFMA bf16 GEMM. out = relu(b + [agg|h] @ W^T), K=256.
// Wave tile M=32 x N=64. Fragments are 16B contiguous global loads.
__global__ __launch_bounds__(256) void layer128_mfma_kernel(
    const bf16_t* __restrict__ aggb, const bf16_t* __restrict__ hin,
    const bf16_t* __restrict__ wbf, const float* __restrict__ bias,
    bf16_t* __restrict__ hout, int n) {
    const int t = threadIdx.x;
    const int lane = t & 63;
    const int wave = t >> 6;
    const int r = lane & 15;
    const int q = lane >> 4;
    const int m0 = blockIdx.x * 64 + (wave >> 1) * 32;
    const int nb = (wave & 1) * 64;

    bf16x8 aF[2][8];
    #pragma unroll
    for (int mt = 0; mt < 2; ++mt) {
        int node = m0 + mt * 16 + r;
        if (node >= n) node = n - 1;                 // clamp; stores predicated
        const bf16_t* arow = aggb + (size_t)node * 128;
        const bf16_t* hrow = hin + (size_t)node * 128;
        #pragma unroll
        for (int ks = 0; ks < 4; ++ks)
            aF[mt][ks] = *(const bf16x8*)(arow + ks * 32 + q * 8);
        #pragma unroll
        for (int ks = 0; ks < 4; ++ks)
            aF[mt][4 + ks] = *(const bf16x8*)(hrow + ks * 32 + q * 8);
    }

    #pragma unroll
    for (int nt = 0; nt < 4; ++nt) {
        const int col = nb + nt * 16 + r;
        const bf16_t* wrow = wbf + (size_t)col * 256;
        f32x4 acc0 = {0.f, 0.f, 0.f, 0.f};
        f32x4 acc1 = {0.f, 0.f, 0.f, 0.f};
        #pragma unroll
        for (int ks = 0; ks < 8; ++ks) {
            bf16x8 bF = *(const bf16x8*)(wrow + ks * 32 + q * 8);
            acc0 = __builtin_amdgcn_mfma_f32_16x16x32_bf16(aF[0][ks], bF, acc0, 0, 0, 0);
            acc1 = __builtin_amdgcn_mfma_f32_16x16x32_bf16(aF[1][ks], bF, acc1, 0, 0, 0);
        }
        float bo = bias[col];
        #pragma unroll
        for (int reg = 0; reg < 4; ++reg) {
            int row0 = m0 + q * 4 + reg;
            if (row0 < n)
                hout[(size_t)row0 * 128 + col] = f2bf(fmaxf(acc0[reg] + bo, 0.0f));
            int row1 = m0 + 16 + q * 4 + reg;
            if (row1 < n)
                hout[(size_t)row1 * 128 + col] = f2bf(fmaxf(acc1[reg] + bo, 0.0f));
        }
    }
}

// head: 128 -> 4 from bf16 h (no relu)
__global__ void head_kernel(const bf16_t* __restrict__ h,
                            const float* __restrict__ Wh,
                            const float* __restrict__ bh,
                            float* __restrict__ out, int n) {
    int idx = blockIdx.x * 256 + threadIdx.x;
    if (idx >= n * 4) return;
    int node = idx >> 2;
    int o = idx & 3;
    const bf16_t* hr = h + (size_t)node * 128;
    const float* wr = Wh + o * 128;
    float acc = bh[o];
    #pragma unroll 4
    for (int f = 0; f < 128; f += 4) {
        acc = fmaf(bf2f(hr[f + 0]), wr[f + 0], acc);
        acc = fmaf(bf2f(hr[f + 1]), wr[f + 1], acc);
        acc = fmaf(bf2f(hr[f + 2]), wr[f + 2], acc);
        acc = fmaf(bf2f(hr[f + 3]), wr[f + 3], acc);
    }
    out[idx] = acc;
}

extern "C" void kernel_launch(void* const* d_in, const int* in_sizes, int n_in,
                              void* d_out, int out_size, void* d_ws, size_t ws_size,
                              hipStream_t stream) {
    const float* x   = (const float*)d_in[0];
    const int*   ei  = (const int*)d_in[1];
    const float* Wl1 = (const float*)d_in[2];
    const float* Wr1 = (const float*)d_in[3];
    const float* b1  = (const float*)d_in[4];
    const float* Wl2 = (const float*)d_in[5];
    const float* Wr2 = (const float*)d_in[6];
    const float* b2  = (const float*)d_in[7];
    const float* Wl3 = (const float*)d_in[8];
    const float* Wr3 = (const float*)d_in[9];
    const float* b3  = (const float*)d_in[10];
    const float* Wh  = (const float*)d_in[11];
    const float* bh  = (const float*)d_in[12];
    float* out = (float*)d_out;

    const int N = in_sizes[0] / 16;
    const int E = in_sizes[1] / 2;
    const int* src = ei;
    const int* dst = ei + E;

    const int nScanBlocks = (N + SCAN_CHUNK - 1) / SCAN_CHUNK;

    int* deg       = (int*)d_ws;                       // N
    int* rowptr    = deg + N;                          // N+1 (pad 8)
    int* cursor    = rowptr + (N + 8);                 // N
    int* blocksum  = cursor + N;                       // pad 64
    int* col       = blocksum + 64;                    // E
    float* inv     = (float*)(col + E);                // N
    float* agg16f  = inv + N;                          // N*16 fp32
    bf16_t* aggb   = (bf16_t*)(agg16f + (size_t)N * 16); // N*128 bf16
    bf16_t* hA     = aggb + (size_t)N * 128;           // N*128 bf16
    bf16_t* hB     = hA + (size_t)N * 128;             // N*128 bf16
    bf16_t* wbf2   = hB + (size_t)N * 128;             // 128*256 bf16
    bf16_t* wbf3   = wbf2 + 128 * 256;                 // 128*256 bf16

    const int B = 256;
    auto blocks = [](long total, int b) { return (int)((total + b - 1) / b); };

    // ---- CSR build + weight conversion ----
    zero_int_kernel<<<blocks(N, B), B, 0, stream>>>(deg, N);
    count_deg_kernel<<<blocks(E, B), B, 0, stream>>>(dst, deg, E);
    convert_w_kernel<<<128, B, 0, stream>>>(Wl2, Wr2, wbf2);
    convert_w_kernel<<<128, B, 0, stream>>>(Wl3, Wr3, wbf3);
    scan_partial_kernel<<<nScanBlocks, B, 0, stream>>>(deg, blocksum, N);
    scan_final_kernel<<<nScanBlocks, B, 0, stream>>>(deg, blocksum, rowptr, cursor, inv, N);
    fill_csr_kernel<<<blocks(E, B), B, 0, stream>>>(src, dst, cursor, col, E);

    // ---- layer 1: 16 -> 128 ----
    aggregate16_kernel<<<blocks(N, 16), B, 0, stream>>>(x, rowptr, col, inv, agg16f, N);
    layer16_kernel<<<blocks((long)N * 16, B), B, 0, stream>>>(agg16f, x, Wl1, Wr1, b1, hA, N);

    // ---- layer 2: 128 -> 128 (MFMA) ----
    aggregate128_kernel<<<blocks(N, 16), B, 0, stream>>>(hA, rowptr, col, inv, aggb, N);
    layer128_mfma_kernel<<<blocks(N, 64), B, 0, stream>>>(aggb, hA, wbf2, b2, hB, N);

    // ---- layer 3: 128 -> 128 (MFMA) ----
    aggregate128_kernel<<<blocks(N, 16), B, 0, stream>>>(hB, rowptr, col, inv, aggb, N);
    layer128_mfma_kernel<<<blocks(N, 64), B, 0, stream>>>(aggb, hB, wbf3, b3, hA, N);

    // ---- head: 128 -> 4 ----
    head_kernel<<<blocks((long)N * 4, B), B, 0, stream>>>(hA, Wh, bh, out, N);
}

// Round 7
// 312.840 us; speedup vs baseline: 1.2878x; 1.2878x over previous
//
#include <hip/hip_runtime.h>
#include <hip/hip_bf16.h>

// ---------------------------------------------------------------------------
// GraphSAGE (3x SAGEConv mean + linear head), CSR gather formulation.
// bf16 activations/aggregates everywhere; ALL three layers are MFMA bf16
// GEMMs with fragments loaded straight from global (weights L1-resident).
// R7: layer16 -> MFMA (K=32, [agg|x] packed by aggregate16). R6's node-major
// layer16 regressed (64 uncoalesced weight loads/thread, VALUBusy 6%).
// ---------------------------------------------------------------------------

#define SCAN_CHUNK 2048

typedef unsigned short bf16_t;
typedef unsigned int uint32;
typedef __attribute__((ext_vector_type(8))) short bf16x8;   // 8 bf16 = 4 VGPRs
typedef __attribute__((ext_vector_type(4))) float f32x4;

__device__ __forceinline__ bf16_t f2bf(float f) {
    uint32 u = __float_as_uint(f);
    u += 0x7fff + ((u >> 16) & 1);           // round-to-nearest-even
    return (bf16_t)(u >> 16);
}
__device__ __forceinline__ float bf2f(bf16_t b) {
    return __uint_as_float((uint32)b << 16);
}

__global__ void zero_int_kernel(int* __restrict__ p, int n) {
    int i = blockIdx.x * 256 + threadIdx.x;
    if (i < n) p[i] = 0;
}

__global__ void count_deg_kernel(const int* __restrict__ dst, int* __restrict__ deg, int E) {
    int e = blockIdx.x * 256 + threadIdx.x;
    if (e < E) atomicAdd(&deg[dst[e]], 1);
}

__global__ __launch_bounds__(256) void scan_partial_kernel(
    const int* __restrict__ deg, int* __restrict__ blocksum, int N) {
    __shared__ int s[256];
    const int t = threadIdx.x;
    const int base = blockIdx.x * SCAN_CHUNK + t * 8;
    int sum = 0;
    #pragma unroll
    for (int j = 0; j < 8; ++j) {
        int i = base + j;
        if (i < N) sum += deg[i];
    }
    s[t] = sum;
    __syncthreads();
    #pragma unroll
    for (int off = 128; off > 0; off >>= 1) {
        if (t < off) s[t] += s[t + off];
        __syncthreads();
    }
    if (t == 0) blocksum[blockIdx.x] = s[0];
}

__global__ __launch_bounds__(256) void scan_final_kernel(
    const int* __restrict__ deg, const int* __restrict__ blocksum,
    int* __restrict__ rowptr, int* __restrict__ cursor,
    float* __restrict__ inv, int N) {
    __shared__ int s[256];
    __shared__ int blockoff_s;
    const int t = threadIdx.x;
    if (t == 0) {
        int off = 0;
        for (int b = 0; b < (int)blockIdx.x; ++b) off += blocksum[b];
        blockoff_s = off;
    }
    const int base = blockIdx.x * SCAN_CHUNK + t * 8;
    int v[8];
    int sum = 0;
    #pragma unroll
    for (int j = 0; j < 8; ++j) {
        int i = base + j;
        v[j] = (i < N) ? deg[i] : 0;
        sum += v[j];
    }
    s[t] = sum;
    __syncthreads();
    for (int off = 1; off < 256; off <<= 1) {
        int val = (t >= off) ? s[t - off] : 0;
        __syncthreads();
        s[t] += val;
        __syncthreads();
    }
    int run = blockoff_s + ((t == 0) ? 0 : s[t - 1]);
    #pragma unroll
    for (int j = 0; j < 8; ++j) {
        int i = base + j;
        if (i < N) {
            rowptr[i] = run;
            cursor[i] = run;
            inv[i] = 1.0f / (float)max(v[j], 1);
            run += v[j];
        }
    }
    if ((int)blockIdx.x == (int)gridDim.x - 1 && t == 255) rowptr[N] = run;
}

__global__ void fill_csr_kernel(const int* __restrict__ src, const int* __restrict__ dst,
                                int* __restrict__ cursor, int* __restrict__ col, int E) {
    int e = blockIdx.x * 256 + threadIdx.x;
    if (e >= E) return;
    int pos = atomicAdd(&cursor[dst[e]], 1);
    col[pos] = src[e];
}

// combine Wl|Wr (fp32, [128][128] each) -> wbf [128 o][256 k] bf16
__global__ void convert_w_kernel(const float* __restrict__ Wl, const float* __restrict__ Wr,
                                 bf16_t* __restrict__ wbf) {
    int idx = blockIdx.x * 256 + threadIdx.x;   // 0..32767
    int o = idx >> 8;
    int k = idx & 255;
    float v = (k < 128) ? Wl[o * 128 + k] : Wr[o * 128 + k - 128];
    wbf[idx] = f2bf(v);
}

// combine Wl1|Wr1 (fp32, [128][16] each) -> wbf1 [128 o][32 k] bf16 (8KB)
__global__ void convert_w1_kernel(const float* __restrict__ Wl, const float* __restrict__ Wr,
                                  bf16_t* __restrict__ wbf1) {
    int idx = blockIdx.x * 256 + threadIdx.x;   // 0..4095
    int o = idx >> 5;
    int k = idx & 31;
    float v = (k < 16) ? Wl[o * 16 + k] : Wr[o * 16 + k - 16];
    wbf1[idx] = f2bf(v);
}

// 16-feat mean aggregate + x pack -> a16[node][32] bf16 ([mean | x])
__global__ __launch_bounds__(256) void aggregate16_kernel(
    const float* __restrict__ x, const int* __restrict__ rowptr,
    const int* __restrict__ col, const float* __restrict__ inv,
    bf16_t* __restrict__ a16, int N) {
    const int t = threadIdx.x;
    const int node = blockIdx.x * 16 + (t >> 4);
    const int f = t & 15;
    if (node >= N) return;
    const int lo = rowptr[node], hi = rowptr[node + 1];
    float acc = 0.0f, acc2 = 0.0f;
    int e = lo;
    for (; e + 1 < hi; e += 2) {             // unroll-2: two loads in flight
        int s0 = col[e], s1 = col[e + 1];
        acc  += x[s0 * 16 + f];
        acc2 += x[s1 * 16 + f];
    }
    if (e < hi) acc += x[col[e] * 16 + f];
    a16[node * 32 + f]      = f2bf((acc + acc2) * inv[node]);
    a16[node * 32 + 16 + f] = f2bf(x[node * 16 + f]);
}

// 128-feat mean aggregate over bf16 h -> bf16 agg.
// 16 lanes/node (16B each), unroll-2: 8 independent row loads per wave.
__global__ __launch_bounds__(256) void aggregate128_kernel(
    const bf16_t* __restrict__ h, const int* __restrict__ rowptr,
    const int* __restrict__ col, const float* __restrict__ inv,
    bf16_t* __restrict__ aggb, int N) {
    const int t = threadIdx.x;
    const int node = blockIdx.x * 16 + (t >> 4);
    const int li = t & 15;
    if (node >= N) return;
    const int lo = rowptr[node], hi = rowptr[node + 1];
    float acc[8];
    #pragma unroll
    for (int j = 0; j < 8; ++j) acc[j] = 0.0f;
    int e = lo;
    for (; e + 1 < hi; e += 2) {
        int s0 = col[e], s1 = col[e + 1];
        uint4 v0 = *(const uint4*)&h[(size_t)s0 * 128 + li * 8];
        uint4 v1 = *(const uint4*)&h[(size_t)s1 * 128 + li * 8];
        acc[0] += bf2f((bf16_t)(v0.x & 0xffff)); acc[1] += bf2f((bf16_t)(v0.x >> 16));
        acc[2] += bf2f((bf16_t)(v0.y & 0xffff)); acc[3] += bf2f((bf16_t)(v0.y >> 16));
        acc[4] += bf2f((bf16_t)(v0.z & 0xffff)); acc[5] += bf2f((bf16_t)(v0.z >> 16));
        acc[6] += bf2f((bf16_t)(v0.w & 0xffff)); acc[7] += bf2f((bf16_t)(v0.w >> 16));
        acc[0] += bf2f((bf16_t)(v1.x & 0xffff)); acc[1] += bf2f((bf16_t)(v1.x >> 16));
        acc[2] += bf2f((bf16_t)(v1.y & 0xffff)); acc[3] += bf2f((bf16_t)(v1.y >> 16));
        acc[4] += bf2f((bf16_t)(v1.z & 0xffff)); acc[5] += bf2f((bf16_t)(v1.z >> 16));
        acc[6] += bf2f((bf16_t)(v1.w & 0xffff)); acc[7] += bf2f((bf16_t)(v1.w >> 16));
    }
    if (e < hi) {
        uint4 v0 = *(const uint4*)&h[(size_t)col[e] * 128 + li * 8];
        acc[0] += bf2f((bf16_t)(v0.x & 0xffff)); acc[1] += bf2f((bf16_t)(v0.x >> 16));
        acc[2] += bf2f((bf16_t)(v0.y & 0xffff)); acc[3] += bf2f((bf16_t)(v0.y >> 16));
        acc[4] += bf2f((bf16_t)(v0.z & 0xffff)); acc[5] += bf2f((bf16_t)(v0.z >> 16));
        acc[6] += bf2f((bf16_t)(v0.w & 0xffff)); acc[7] += bf2f((bf16_t)(v0.w >> 16));
    }
    const float iv = inv[node];
    uint4 pk;
    pk.x = (uint32)f2bf(acc[0] * iv) | ((uint32)f2bf(acc[1] * iv) << 16);
    pk.y = (uint32)f2bf(acc[2] * iv) | ((uint32)f2bf(acc[3] * iv) << 16);
    pk.z = (uint32)f2bf(acc[4] * iv) | ((uint32)f2bf(acc[5] * iv) << 16);
    pk.w = (uint32)f2bf(acc[6] * iv) | ((uint32)f2bf(acc[7] * iv) << 16);
    *(uint4*)&aggb[(size_t)node * 128 + li * 8] = pk;
}

// layer 1 as MFMA: out = relu(b + [agg|x] @ [Wl1|Wr1]^T), K=32 (one k-step).
// Wave tile M=32 x N=64, same skeleton as layer128_mfma_kernel.
__global__ __launch_bounds__(256) void layer16_mfma_kernel(
    const bf16_t* __restrict__ a16, const bf16_t* __restrict__ wbf1,
    const float* __restrict__ bias, bf16_t* __restrict__ hout, int n) {
    const int t = threadIdx.x;
    const int lane = t & 63;
    const int wave = t >> 6;
    const int r = lane & 15;
    const int q = lane >> 4;
    const int m0 = blockIdx.x * 64 + (wave >> 1) * 32;
    const int nb = (wave & 1) * 64;

    bf16x8 aF[2];
    #pragma unroll
    for (int mt = 0; mt < 2; ++mt) {
        int node = m0 + mt * 16 + r;
        if (node >= n) node = n - 1;                 // clamp; stores predicated
        aF[mt] = *(const bf16x8*)(a16 + (size_t)node * 32 + q * 8);
    }

    #pragma unroll
    for (int nt = 0; nt < 4; ++nt) {
        const int col = nb + nt * 16 + r;
        bf16x8 bF = *(const bf16x8*)(wbf1 + (size_t)col * 32 + q * 8);
        f32x4 acc0 = {0.f, 0.f, 0.f, 0.f};
        f32x4 acc1 = {0.f, 0.f, 0.f, 0.f};
        acc0 = __builtin_amdgcn_mfma_f32_16x16x32_bf16(aF[0], bF, acc0, 0, 0, 0);
        acc1 = __builtin_amdgcn_mfma_f32_16x16x32_bf16(aF[1], bF, acc1, 0, 0, 0);
        float bo = bias[col];
        #pragma unroll
        for (int reg = 0; reg < 4; ++reg) {
            int row0 = m0 + q * 4 + reg;
            if (row0 < n)
                hout[(size_t)row0 * 128 + col] = f2bf(fmaxf(acc0[reg] + bo, 0.0f));
            int row1 = m0 + 16 + q * 4 + reg;
            if (row1 < n)
                hout[(size_t)row1 * 128 + col] = f2bf(fmaxf(acc1[reg] + bo, 0.0f));
        }
    }
}

// layers 2/3 as MFMA bf16 GEMM. out = relu(b + [agg|h] @ W^T), K=256.
__global__ __launch_bounds__(256) void layer128_mfma_kernel(
    const bf16_t* __restrict__ aggb, const bf16_t* __restrict__ hin,
    const bf16_t* __restrict__ wbf, const float* __restrict__ bias,
    bf16_t* __restrict__ hout, int n) {
    const int t = threadIdx.x;
    const int lane = t & 63;
    const int wave = t >> 6;
    const int r = lane & 15;
    const int q = lane >> 4;
    const int m0 = blockIdx.x * 64 + (wave >> 1) * 32;
    const int nb = (wave & 1) * 64;

    bf16x8 aF[2][8];
    #pragma unroll
    for (int mt = 0; mt < 2; ++mt) {
        int node = m0 + mt * 16 + r;
        if (node >= n) node = n - 1;
        const bf16_t* arow = aggb + (size_t)node * 128;
        const bf16_t* hrow = hin + (size_t)node * 128;
        #pragma unroll
        for (int ks = 0; ks < 4; ++ks)
            aF[mt][ks] = *(const bf16x8*)(arow + ks * 32 + q * 8);
        #pragma unroll
        for (int ks = 0; ks < 4; ++ks)
            aF[mt][4 + ks] = *(const bf16x8*)(hrow + ks * 32 + q * 8);
    }

    #pragma unroll
    for (int nt = 0; nt < 4; ++nt) {
        const int col = nb + nt * 16 + r;
        const bf16_t* wrow = wbf + (size_t)col * 256;
        f32x4 acc0 = {0.f, 0.f, 0.f, 0.f};
        f32x4 acc1 = {0.f, 0.f, 0.f, 0.f};
        #pragma unroll
        for (int ks = 0; ks < 8; ++ks) {
            bf16x8 bF = *(const bf16x8*)(wrow + ks * 32 + q * 8);
            acc0 = __builtin_amdgcn_mfma_f32_16x16x32_bf16(aF[0][ks], bF, acc0, 0, 0, 0);
            acc1 = __builtin_amdgcn_mfma_f32_16x16x32_bf16(aF[1][ks], bF, acc1, 0, 0, 0);
        }
        float bo = bias[col];
        #pragma unroll
        for (int reg = 0; reg < 4; ++reg) {
            int row0 = m0 + q * 4 + reg;
            if (row0 < n)
                hout[(size_t)row0 * 128 + col] = f2bf(fmaxf(acc0[reg] + bo, 0.0f));
            int row1 = m0 + 16 + q * 4 + reg;
            if (row1 < n)
                hout[(size_t)row1 * 128 + col] = f2bf(fmaxf(acc1[reg] + bo, 0.0f));
        }
    }
}

// head: 128 -> 4 from bf16 h (no relu)
__global__ void head_kernel(const bf16_t* __restrict__ h,
                            const float* __restrict__ Wh,
                            const float* __restrict__ bh,
                            float* __restrict__ out, int n) {
    int idx = blockIdx.x * 256 + threadIdx.x;
    if (idx >= n * 4) return;
    int node = idx >> 2;
    int o = idx & 3;
    const bf16_t* hr = h + (size_t)node * 128;
    const float* wr = Wh + o * 128;
    float acc = bh[o];
    #pragma unroll 4
    for (int f = 0; f < 128; f += 4) {
        acc = fmaf(bf2f(hr[f + 0]), wr[f + 0], acc);
        acc = fmaf(bf2f(hr[f + 1]), wr[f + 1], acc);
        acc = fmaf(bf2f(hr[f + 2]), wr[f + 2], acc);
        acc = fmaf(bf2f(hr[f + 3]), wr[f + 3], acc);
    }
    out[idx] = acc;
}

extern "C" void kernel_launch(void* const* d_in, const int* in_sizes, int n_in,
                              void* d_out, int out_size, void* d_ws, size_t ws_size,
                              hipStream_t stream) {
    const float* x   = (const float*)d_in[0];
    const int*   ei  = (const int*)d_in[1];
    const float* Wl1 = (const float*)d_in[2];
    const float* Wr1 = (const float*)d_in[3];
    const float* b1  = (const float*)d_in[4];
    const float* Wl2 = (const float*)d_in[5];
    const float* Wr2 = (const float*)d_in[6];
    const float* b2  = (const float*)d_in[7];
    const float* Wl3 = (const float*)d_in[8];
    const float* Wr3 = (const float*)d_in[9];
    const float* b3  = (const float*)d_in[10];
    const float* Wh  = (const float*)d_in[11];
    const float* bh  = (const float*)d_in[12];
    float* out = (float*)d_out;

    const int N = in_sizes[0] / 16;
    const int E = in_sizes[1] / 2;
    const int* src = ei;
    const int* dst = ei + E;

    const int nScanBlocks = (N + SCAN_CHUNK - 1) / SCAN_CHUNK;

    int* deg       = (int*)d_ws;                       // N
    int* rowptr    = deg + N;                          // N+1 (pad 8)
    int* cursor    = rowptr + (N + 8);                 // N
    int* blocksum  = cursor + N;                       // pad 64
    int* col       = blocksum + 64;                    // E
    float* inv     = (float*)(col + E);                // N
    bf16_t* a16    = (bf16_t*)(inv + N);               // N*32 bf16
    bf16_t* aggb   = a16 + (size_t)N * 32;             // N*128 bf16
    bf16_t* hA     = aggb + (size_t)N * 128;           // N*128 bf16
    bf16_t* hB     = hA + (size_t)N * 128;             // N*128 bf16
    bf16_t* wbf1   = hB + (size_t)N * 128;             // 128*32 bf16
    bf16_t* wbf2   = wbf1 + 128 * 32;                  // 128*256 bf16
    bf16_t* wbf3   = wbf2 + 128 * 256;                 // 128*256 bf16

    const int B = 256;
    auto blocks = [](long total, int b) { return (int)((total + b - 1) / b); };

    // ---- CSR build + weight conversion ----
    zero_int_kernel<<<blocks(N, B), B, 0, stream>>>(deg, N);
    count_deg_kernel<<<blocks(E, B), B, 0, stream>>>(dst, deg, E);
    convert_w1_kernel<<<16, B, 0, stream>>>(Wl1, Wr1, wbf1);
    convert_w_kernel<<<128, B, 0, stream>>>(Wl2, Wr2, wbf2);
    convert_w_kernel<<<128, B, 0, stream>>>(Wl3, Wr3, wbf3);
    scan_partial_kernel<<<nScanBlocks, B, 0, stream>>>(deg, blocksum, N);
    scan_final_kernel<<<nScanBlocks, B, 0, stream>>>(deg, blocksum, rowptr, cursor, inv, N);
    fill_csr_kernel<<<blocks(E, B), B, 0, stream>>>(src, dst, cursor, col, E);

    // ---- layer 1: 16 -> 128 (MFMA, K=32) ----
    aggregate16_kernel<<<blocks(N, 16), B, 0, stream>>>(x, rowptr, col, inv, a16, N);
    layer16_mfma_kernel<<<blocks(N, 64), B, 0, stream>>>(a16, wbf1, b1, hA, N);

    // ---- layer 2: 128 -> 128 (MFMA, K=256) ----
    aggregate128_kernel<<<blocks(N, 16), B, 0, stream>>>(hA, rowptr, col, inv, aggb, N);
    layer128_mfma_kernel<<<blocks(N, 64), B, 0, stream>>>(aggb, hA, wbf2, b2, hB, N);

    // ---- layer 3: 128 -> 128 (MFMA, K=256) ----
    aggregate128_kernel<<<blocks(N, 16), B, 0, stream>>>(hB, rowptr, col, inv, aggb, N);
    layer128_mfma_kernel<<<blocks(N, 64), B, 0, stream>>>(aggb, hB, wbf3, b3, hA, N);

    // ---- head: 128 -> 4 ----
    head_kernel<<<blocks((long)N * 4, B), B, 0, stream>>>(hA, Wh, bh, out, N);
}

// Round 8
// 299.492 us; speedup vs baseline: 1.3452x; 1.0446x over previous
//
#include <hip/hip_runtime.h>
#include <hip/hip_bf16.h>

// ---------------------------------------------------------------------------
// GraphSAGE (3x SAGEConv mean + linear head), CSR gather formulation.
// bf16 activations/aggregates; all layers are MFMA bf16 GEMMs, fragments
// straight from global (weights L1-resident, no LDS in the K-loop).
// R8: aggregate unroll-4 (gathers are latency-bound, avg deg 12);
//     head fused into layer-3 GEMM via LDS tile (saves h3 write+read+launch).
// Note: top-5 profile entries are the harness's 0xAA workspace poison fill
// (~45us, 268MB) — not controllable from here.
// ---------------------------------------------------------------------------

#define SCAN_CHUNK 2048

typedef unsigned short bf16_t;
typedef unsigned int uint32;
typedef __attribute__((ext_vector_type(8))) short bf16x8;   // 8 bf16 = 4 VGPRs
typedef __attribute__((ext_vector_type(4))) float f32x4;

__device__ __forceinline__ bf16_t f2bf(float f) {
    uint32 u = __float_as_uint(f);
    u += 0x7fff + ((u >> 16) & 1);           // round-to-nearest-even
    return (bf16_t)(u >> 16);
}
__device__ __forceinline__ float bf2f(bf16_t b) {
    return __uint_as_float((uint32)b << 16);
}

__global__ void zero_int_kernel(int* __restrict__ p, int n) {
    int i = blockIdx.x * 256 + threadIdx.x;
    if (i < n) p[i] = 0;
}

__global__ void count_deg_kernel(const int* __restrict__ dst, int* __restrict__ deg, int E) {
    int e = blockIdx.x * 256 + threadIdx.x;
    if (e < E) atomicAdd(&deg[dst[e]], 1);
}

__global__ __launch_bounds__(256) void scan_partial_kernel(
    const int* __restrict__ deg, int* __restrict__ blocksum, int N) {
    __shared__ int s[256];
    const int t = threadIdx.x;
    const int base = blockIdx.x * SCAN_CHUNK + t * 8;
    int sum = 0;
    #pragma unroll
    for (int j = 0; j < 8; ++j) {
        int i = base + j;
        if (i < N) sum += deg[i];
    }
    s[t] = sum;
    __syncthreads();
    #pragma unroll
    for (int off = 128; off > 0; off >>= 1) {
        if (t < off) s[t] += s[t + off];
        __syncthreads();
    }
    if (t == 0) blocksum[blockIdx.x] = s[0];
}

__global__ __launch_bounds__(256) void scan_final_kernel(
    const int* __restrict__ deg, const int* __restrict__ blocksum,
    int* __restrict__ rowptr, int* __restrict__ cursor,
    float* __restrict__ inv, int N) {
    __shared__ int s[256];
    __shared__ int blockoff_s;
    const int t = threadIdx.x;
    if (t == 0) {
        int off = 0;
        for (int b = 0; b < (int)blockIdx.x; ++b) off += blocksum[b];
        blockoff_s = off;
    }
    const int base = blockIdx.x * SCAN_CHUNK + t * 8;
    int v[8];
    int sum = 0;
    #pragma unroll
    for (int j = 0; j < 8; ++j) {
        int i = base + j;
        v[j] = (i < N) ? deg[i] : 0;
        sum += v[j];
    }
    s[t] = sum;
    __syncthreads();
    for (int off = 1; off < 256; off <<= 1) {
        int val = (t >= off) ? s[t - off] : 0;
        __syncthreads();
        s[t] += val;
        __syncthreads();
    }
    int run = blockoff_s + ((t == 0) ? 0 : s[t - 1]);
    #pragma unroll
    for (int j = 0; j < 8; ++j) {
        int i = base + j;
        if (i < N) {
            rowptr[i] = run;
            cursor[i] = run;
            inv[i] = 1.0f / (float)max(v[j], 1);
            run += v[j];
        }
    }
    if ((int)blockIdx.x == (int)gridDim.x - 1 && t == 255) rowptr[N] = run;
}

__global__ void fill_csr_kernel(const int* __restrict__ src, const int* __restrict__ dst,
                                int* __restrict__ cursor, int* __restrict__ col, int E) {
    int e = blockIdx.x * 256 + threadIdx.x;
    if (e >= E) return;
    int pos = atomicAdd(&cursor[dst[e]], 1);
    col[pos] = src[e];
}

// combine Wl|Wr (fp32, [128][128] each) -> wbf [128 o][256 k] bf16
__global__ void convert_w_kernel(const float* __restrict__ Wl, const float* __restrict__ Wr,
                                 bf16_t* __restrict__ wbf) {
    int idx = blockIdx.x * 256 + threadIdx.x;
    int o = idx >> 8;
    int k = idx & 255;
    float v = (k < 128) ? Wl[o * 128 + k] : Wr[o * 128 + k - 128];
    wbf[idx] = f2bf(v);
}

// combine Wl1|Wr1 (fp32, [128][16] each) -> wbf1 [128 o][32 k] bf16 (8KB)
__global__ void convert_w1_kernel(const float* __restrict__ Wl, const float* __restrict__ Wr,
                                  bf16_t* __restrict__ wbf1) {
    int idx = blockIdx.x * 256 + threadIdx.x;
    int o = idx >> 5;
    int k = idx & 31;
    float v = (k < 16) ? Wl[o * 16 + k] : Wr[o * 16 + k - 16];
    wbf1[idx] = f2bf(v);
}

// 16-feat mean aggregate + x pack -> a16[node][32] bf16 ([mean | x]), unroll-4
__global__ __launch_bounds__(256) void aggregate16_kernel(
    const float* __restrict__ x, const int* __restrict__ rowptr,
    const int* __restrict__ col, const float* __restrict__ inv,
    bf16_t* __restrict__ a16, int N) {
    const int t = threadIdx.x;
    const int node = blockIdx.x * 16 + (t >> 4);
    const int f = t & 15;
    if (node >= N) return;
    const int lo = rowptr[node], hi = rowptr[node + 1];
    float a0 = 0.f, a1 = 0.f, a2 = 0.f, a3 = 0.f;
    int e = lo;
    for (; e + 3 < hi; e += 4) {
        int s0 = col[e], s1 = col[e + 1], s2 = col[e + 2], s3 = col[e + 3];
        a0 += x[s0 * 16 + f];
        a1 += x[s1 * 16 + f];
        a2 += x[s2 * 16 + f];
        a3 += x[s3 * 16 + f];
    }
    for (; e < hi; ++e) a0 += x[col[e] * 16 + f];
    a16[node * 32 + f]      = f2bf((a0 + a1 + a2 + a3) * inv[node]);
    a16[node * 32 + 16 + f] = f2bf(x[node * 16 + f]);
}

// 128-feat mean aggregate over bf16 h -> bf16 agg. 16 lanes/node (16B each),
// unroll-4: up to 16 independent row loads in flight per wave.
__device__ __forceinline__ void acc_row(float* acc, uint4 v) {
    acc[0] += bf2f((bf16_t)(v.x & 0xffff)); acc[1] += bf2f((bf16_t)(v.x >> 16));
    acc[2] += bf2f((bf16_t)(v.y & 0xffff)); acc[3] += bf2f((bf16_t)(v.y >> 16));
    acc[4] += bf2f((bf16_t)(v.z & 0xffff)); acc[5] += bf2f((bf16_t)(v.z >> 16));
    acc[6] += bf2f((bf16_t)(v.w & 0xffff)); acc[7] += bf2f((bf16_t)(v.w >> 16));
}

__global__ __launch_bounds__(256) void aggregate128_kernel(
    const bf16_t* __restrict__ h, const int* __restrict__ rowptr,
    const int* __restrict__ col, const float* __restrict__ inv,
    bf16_t* __restrict__ aggb, int N) {
    const int t = threadIdx.x;
    const int node = blockIdx.x * 16 + (t >> 4);
    const int li = t & 15;
    if (node >= N) return;
    const int lo = rowptr[node], hi = rowptr[node + 1];
    float acc[8];
    #pragma unroll
    for (int j = 0; j < 8; ++j) acc[j] = 0.0f;
    int e = lo;
    for (; e + 3 < hi; e += 4) {
        int s0 = col[e], s1 = col[e + 1], s2 = col[e + 2], s3 = col[e + 3];
        uint4 v0 = *(const uint4*)&h[(size_t)s0 * 128 + li * 8];
        uint4 v1 = *(const uint4*)&h[(size_t)s1 * 128 + li * 8];
        uint4 v2 = *(const uint4*)&h[(size_t)s2 * 128 + li * 8];
        uint4 v3 = *(const uint4*)&h[(size_t)s3 * 128 + li * 8];
        acc_row(acc, v0);
        acc_row(acc, v1);
        acc_row(acc, v2);
        acc_row(acc, v3);
    }
    for (; e < hi; ++e) {
        uint4 v0 = *(const uint4*)&h[(size_t)col[e] * 128 + li * 8];
        acc_row(acc, v0);
    }
    const float iv = inv[node];
    uint4 pk;
    pk.x = (uint32)f2bf(acc[0] * iv) | ((uint32)f2bf(acc[1] * iv) << 16);
    pk.y = (uint32)f2bf(acc[2] * iv) | ((uint32)f2bf(acc[3] * iv) << 16);
    pk.z = (uint32)f2bf(acc[4] * iv) | ((uint32)f2bf(acc[5] * iv) << 16);
    pk.w = (uint32)f2bf(acc[6] * iv) | ((uint32)f2bf(acc[7] * iv) << 16);
    *(uint4*)&aggb[(size_t)node * 128 + li * 8] = pk;
}

// layer 1 as MFMA: out = relu(b + [agg|x] @ [Wl1|Wr1]^T), K=32.
__global__ __launch_bounds__(256) void layer16_mfma_kernel(
    const bf16_t* __restrict__ a16, const bf16_t* __restrict__ wbf1,
    const float* __restrict__ bias, bf16_t* __restrict__ hout, int n) {
    const int t = threadIdx.x;
    const int lane = t & 63;
    const int wave = t >> 6;
    const int r = lane & 15;
    const int q = lane >> 4;
    const int m0 = blockIdx.x * 64 + (wave >> 1) * 32;
    const int nb = (wave & 1) * 64;

    bf16x8 aF[2];
    #pragma unroll
    for (int mt = 0; mt < 2; ++mt) {
        int node = m0 + mt * 16 + r;
        if (node >= n) node = n - 1;
        aF[mt] = *(const bf16x8*)(a16 + (size_t)node * 32 + q * 8);
    }

    #pragma unroll
    for (int nt = 0; nt < 4; ++nt) {
        const int col = nb + nt * 16 + r;
        bf16x8 bF = *(const bf16x8*)(wbf1 + (size_t)col * 32 + q * 8);
        f32x4 acc0 = {0.f, 0.f, 0.f, 0.f};
        f32x4 acc1 = {0.f, 0.f, 0.f, 0.f};
        acc0 = __builtin_amdgcn_mfma_f32_16x16x32_bf16(aF[0], bF, acc0, 0, 0, 0);
        acc1 = __builtin_amdgcn_mfma_f32_16x16x32_bf16(aF[1], bF, acc1, 0, 0, 0);
        float bo = bias[col];
        #pragma unroll
        for (int reg = 0; reg < 4; ++reg) {
            int row0 = m0 + q * 4 + reg;
            if (row0 < n)
                hout[(size_t)row0 * 128 + col] = f2bf(fmaxf(acc0[reg] + bo, 0.0f));
            int row1 = m0 + 16 + q * 4 + reg;
            if (row1 < n)
                hout[(size_t)row1 * 128 + col] = f2bf(fmaxf(acc1[reg] + bo, 0.0f));
        }
    }
}

// layer 2 as MFMA bf16 GEMM. out = relu(b + [agg|h] @ W^T), K=256.
__global__ __launch_bounds__(256) void layer128_mfma_kernel(
    const bf16_t* __restrict__ aggb, const bf16_t* __restrict__ hin,
    const bf16_t* __restrict__ wbf, const float* __restrict__ bias,
    bf16_t* __restrict__ hout, int n) {
    const int t = threadIdx.x;
    const int lane = t & 63;
    const int wave = t >> 6;
    const int r = lane & 15;
    const int q = lane >> 4;
    const int m0 = blockIdx.x * 64 + (wave >> 1) * 32;
    const int nb = (wave & 1) * 64;

    bf16x8 aF[2][8];
    #pragma unroll
    for (int mt = 0; mt < 2; ++mt) {
        int node = m0 + mt * 16 + r;
        if (node >= n) node = n - 1;
        const bf16_t* arow = aggb + (size_t)node * 128;
        const bf16_t* hrow = hin + (size_t)node * 128;
        #pragma unroll
        for (int ks = 0; ks < 4; ++ks)
            aF[mt][ks] = *(const bf16x8*)(arow + ks * 32 + q * 8);
        #pragma unroll
        for (int ks = 0; ks < 4; ++ks)
            aF[mt][4 + ks] = *(const bf16x8*)(hrow + ks * 32 + q * 8);
    }

    #pragma unroll
    for (int nt = 0; nt < 4; ++nt) {
        const int col = nb + nt * 16 + r;
        const bf16_t* wrow = wbf + (size_t)col * 256;
        f32x4 acc0 = {0.f, 0.f, 0.f, 0.f};
        f32x4 acc1 = {0.f, 0.f, 0.f, 0.f};
        #pragma unroll
        for (int ks = 0; ks < 8; ++ks) {
            bf16x8 bF = *(const bf16x8*)(wrow + ks * 32 + q * 8);
            acc0 = __builtin_amdgcn_mfma_f32_16x16x32_bf16(aF[0][ks], bF, acc0, 0, 0, 0);
            acc1 = __builtin_amdgcn_mfma_f32_16x16x32_bf16(aF[1][ks], bF, acc1, 0, 0, 0);
        }
        float bo = bias[col];
        #pragma unroll
        for (int reg = 0; reg < 4; ++reg) {
            int row0 = m0 + q * 4 + reg;
            if (row0 < n)
                hout[(size_t)row0 * 128 + col] = f2bf(fmaxf(acc0[reg] + bo, 0.0f));
            int row1 = m0 + 16 + q * 4 + reg;
            if (row1 < n)
                hout[(size_t)row1 * 128 + col] = f2bf(fmaxf(acc1[reg] + bo, 0.0f));
        }
    }
}

// layer 3 + head fused: GEMM epilogue lands the relu'd 64x128 h3 tile in LDS
// (padded [64][132] bf16: q-row-groups offset banks by 8, max 2-way = free),
// then thread=(node,o) computes out[node,o] = bh[o] + h3[node,:] . Wh[o,:].
// h3 never touches global.
__global__ __launch_bounds__(256) void layer128_head_mfma_kernel(
    const bf16_t* __restrict__ aggb, const bf16_t* __restrict__ hin,
    const bf16_t* __restrict__ wbf, const float* __restrict__ bias,
    const float* __restrict__ Wh, const float* __restrict__ bh,
    float* __restrict__ out, int n) {
    __shared__ bf16_t hs[64][132];

    const int t = threadIdx.x;
    const int lane = t & 63;
    const int wave = t >> 6;
    const int r = lane & 15;
    const int q = lane >> 4;
    const int n0 = blockIdx.x * 64;
    const int m0 = n0 + (wave >> 1) * 32;
    const int nb = (wave & 1) * 64;

    bf16x8 aF[2][8];
    #pragma unroll
    for (int mt = 0; mt < 2; ++mt) {
        int node = m0 + mt * 16 + r;
        if (node >= n) node = n - 1;
        const bf16_t* arow = aggb + (size_t)node * 128;
        const bf16_t* hrow = hin + (size_t)node * 128;
        #pragma unroll
        for (int ks = 0; ks < 4; ++ks)
            aF[mt][ks] = *(const bf16x8*)(arow + ks * 32 + q * 8);
        #pragma unroll
        for (int ks = 0; ks < 4; ++ks)
            aF[mt][4 + ks] = *(const bf16x8*)(hrow + ks * 32 + q * 8);
    }

    const int mloc = (wave >> 1) * 32;   // wave's node offset within block tile
    #pragma unroll
    for (int nt = 0; nt < 4; ++nt) {
        const int col = nb + nt * 16 + r;
        const bf16_t* wrow = wbf + (size_t)col * 256;
        f32x4 acc0 = {0.f, 0.f, 0.f, 0.f};
        f32x4 acc1 = {0.f, 0.f, 0.f, 0.f};
        #pragma unroll
        for (int ks = 0; ks < 8; ++ks) {
            bf16x8 bF = *(const bf16x8*)(wrow + ks * 32 + q * 8);
            acc0 = __builtin_amdgcn_mfma_f32_16x16x32_bf16(aF[0][ks], bF, acc0, 0, 0, 0);
            acc1 = __builtin_amdgcn_mfma_f32_16x16x32_bf16(aF[1][ks], bF, acc1, 0, 0, 0);
        }
        float bo = bias[col];
        #pragma unroll
        for (int reg = 0; reg < 4; ++reg) {
            hs[mloc + q * 4 + reg][col]      = f2bf(fmaxf(acc0[reg] + bo, 0.0f));
            hs[mloc + 16 + q * 4 + reg][col] = f2bf(fmaxf(acc1[reg] + bo, 0.0f));
        }
    }
    __syncthreads();

    // head: thread t -> node_local = t>>2, o = t&3
    const int nl = t >> 2;
    const int o  = t & 3;
    const int node = n0 + nl;
    if (node >= n) return;
    const float* wr = Wh + o * 128;
    float acc = bh[o];
    #pragma unroll
    for (int kb = 0; kb < 16; ++kb) {
        bf16x8 hv = *(const bf16x8*)&hs[nl][kb * 8];
        float4 w0 = *(const float4*)&wr[kb * 8];
        float4 w1 = *(const float4*)&wr[kb * 8 + 4];
        acc = fmaf(bf2f((bf16_t)hv[0]), w0.x, acc);
        acc = fmaf(bf2f((bf16_t)hv[1]), w0.y, acc);
        acc = fmaf(bf2f((bf16_t)hv[2]), w0.z, acc);
        acc = fmaf(bf2f((bf16_t)hv[3]), w0.w, acc);
        acc = fmaf(bf2f((bf16_t)hv[4]), w1.x, acc);
        acc = fmaf(bf2f((bf16_t)hv[5]), w1.y, acc);
        acc = fmaf(bf2f((bf16_t)hv[6]), w1.z, acc);
        acc = fmaf(bf2f((bf16_t)hv[7]), w1.w, acc);
    }
    out[(size_t)node * 4 + o] = acc;
}

extern "C" void kernel_launch(void* const* d_in, const int* in_sizes, int n_in,
                              void* d_out, int out_size, void* d_ws, size_t ws_size,
                              hipStream_t stream) {
    const float* x   = (const float*)d_in[0];
    const int*   ei  = (const int*)d_in[1];
    const float* Wl1 = (const float*)d_in[2];
    const float* Wr1 = (const float*)d_in[3];
    const float* b1  = (const float*)d_in[4];
    const float* Wl2 = (const float*)d_in[5];
    const float* Wr2 = (const float*)d_in[6];
    const float* b2  = (const float*)d_in[7];
    const float* Wl3 = (const float*)d_in[8];
    const float* Wr3 = (const float*)d_in[9];
    const float* b3  = (const float*)d_in[10];
    const float* Wh  = (const float*)d_in[11];
    const float* bh  = (const float*)d_in[12];
    float* out = (float*)d_out;

    const int N = in_sizes[0] / 16;
    const int E = in_sizes[1] / 2;
    const int* src = ei;
    const int* dst = ei + E;

    const int nScanBlocks = (N + SCAN_CHUNK - 1) / SCAN_CHUNK;

    int* deg       = (int*)d_ws;                       // N
    int* rowptr    = deg + N;                          // N+1 (pad 8)
    int* cursor    = rowptr + (N + 8);                 // N
    int* blocksum  = cursor + N;                       // pad 64
    int* col       = blocksum + 64;                    // E
    float* inv     = (float*)(col + E);                // N
    bf16_t* a16    = (bf16_t*)(inv + N);               // N*32 bf16
    bf16_t* aggb   = a16 + (size_t)N * 32;             // N*128 bf16
    bf16_t* hA     = aggb + (size_t)N * 128;           // N*128 bf16
    bf16_t* hB     = hA + (size_t)N * 128;             // N*128 bf16
    bf16_t* wbf1   = hB + (size_t)N * 128;             // 128*32 bf16
    bf16_t* wbf2   = wbf1 + 128 * 32;                  // 128*256 bf16
    bf16_t* wbf3   = wbf2 + 128 * 256;                 // 128*256 bf16

    const int B = 256;
    auto blocks = [](long total, int b) { return (int)((total + b - 1) / b); };

    // ---- CSR build + weight conversion ----
    zero_int_kernel<<<blocks(N, B), B, 0, stream>>>(deg, N);
    count_deg_kernel<<<blocks(E, B), B, 0, stream>>>(dst, deg, E);
    convert_w1_kernel<<<16, B, 0, stream>>>(Wl1, Wr1, wbf1);
    convert_w_kernel<<<128, B, 0, stream>>>(Wl2, Wr2, wbf2);
    convert_w_kernel<<<128, B, 0, stream>>>(Wl3, Wr3, wbf3);
    scan_partial_kernel<<<nScanBlocks, B, 0, stream>>>(deg, blocksum, N);
    scan_final_kernel<<<nScanBlocks, B, 0, stream>>>(deg, blocksum, rowptr, cursor, inv, N);
    fill_csr_kernel<<<blocks(E, B), B, 0, stream>>>(src, dst, cursor, col, E);

    // ---- layer 1: 16 -> 128 (MFMA, K=32) ----
    aggregate16_kernel<<<blocks(N, 16), B, 0, stream>>>(x, rowptr, col, inv, a16, N);
    layer16_mfma_kernel<<<blocks(N, 64), B, 0, stream>>>(a16, wbf1, b1, hA, N);

    // ---- layer 2: 128 -> 128 (MFMA, K=256) ----
    aggregate128_kernel<<<blocks(N, 16), B, 0, stream>>>(hA, rowptr, col, inv, aggb, N);
    layer128_mfma_kernel<<<blocks(N, 64), B, 0, stream>>>(aggb, hA, wbf2, b2, hB, N);

    // ---- layer 3 + head fused (MFMA + LDS head) ----
    aggregate128_kernel<<<blocks(N, 16), B, 0, stream>>>(hB, rowptr, col, inv, aggb, N);
    layer128_head_mfma_kernel<<<blocks(N, 64), B, 0, stream>>>(
        aggb, hB, wbf3, b3, Wh, bh, out, N);
}